// Round 13
// baseline (318.095 us; speedup 1.0000x reference)
//
#include <hip/hip_runtime.h>

#define INV_SQRT2f 0.70710678118654752440f

// Analysis filters; synthesis filter f[k] = AF[9-k] (time reversal).
// Polyphase synthesis: out[2q+p] = sum_{j=0..4} AF[9-(2j+p)] * x[(q+2-j) mod Nin]
// Scatter form (verified R3/R11): col-row r adds acc[2t+p] += AF[2(r-t)+1-p]*v, t in [r-4,r]&[0,7]
__constant__ float c_FAR[2][2][10] = {
  {{0.0f, -0.08838834764832f, 0.08838834764832f, 0.69587998903400f, 0.69587998903400f,
    0.08838834764832f, -0.08838834764832f, 0.01122679215254f, 0.01122679215254f, 0.0f},
   {0.0f, -0.01122679215254f, 0.01122679215254f, 0.08838834764832f, 0.08838834764832f,
    -0.69587998903400f, 0.69587998903400f, -0.08838834764832f, -0.08838834764832f, 0.0f}},
  {{0.01122679215254f, 0.01122679215254f, -0.08838834764832f, 0.08838834764832f, 0.69587998903400f,
    0.69587998903400f, 0.08838834764832f, -0.08838834764832f, 0.0f, 0.0f},
   {0.0f, 0.0f, -0.08838834764832f, -0.08838834764832f, 0.69587998903400f,
    -0.69587998903400f, 0.08838834764832f, 0.08838834764832f, 0.01122679215254f, -0.01122679215254f}}
};
__constant__ float c_DUAL[2][2][10] = {
  {{0.03516384f, 0.0f, -0.08832942f, 0.23389032f, 0.76027237f,
    0.58751830f, 0.0f, -0.11430184f, 0.0f, 0.0f},
   {0.0f, 0.0f, -0.11430184f, 0.0f, 0.58751830f,
    -0.76027237f, 0.23389032f, 0.08832942f, 0.0f, -0.03516384f}},
  {{0.0f, 0.0f, -0.11430184f, 0.0f, 0.58751830f,
    0.76027237f, 0.23389032f, -0.08832942f, 0.0f, 0.03516384f},
   {-0.03516384f, 0.0f, 0.08832942f, 0.23389032f, -0.76027237f,
    0.58751830f, 0.0f, -0.11430184f, 0.0f, 0.0f}}
};

// ---- staging: 12x12 spatial halo tile x 16 ch = 576 float4, 256 threads ----
template<int NSZ>
__device__ __forceinline__ void stage_copy(const float* __restrict__ src, float* __restrict__ dst,
                                           int ih0, int iw0, int tid) {
  #pragma unroll
  for (int it = 0; it < 3; ++it) {
    int e = tid + (it << 8);
    if (it < 2 || e < 576) {
      int r = e / 48;
      int cc = e - r * 48;
      int gr = (ih0 + r - 2) & (NSZ - 1);
      int gc = (iw0 + (cc >> 2) - 2) & (NSZ - 1);
      float4 v = *reinterpret_cast<const float4*>(src + (((size_t)gr * NSZ + gc) << 4) + ((cc & 3) << 2));
      *reinterpret_cast<float4*>(dst + (e << 2)) = v;
    }
  }
}

template<int NSZ>
__device__ __forceinline__ void stage_mix(const float* __restrict__ A, const float* __restrict__ B,
                                          float sgn, float* __restrict__ dst,
                                          int ih0, int iw0, int tid) {
  #pragma unroll
  for (int it = 0; it < 3; ++it) {
    int e = tid + (it << 8);
    if (it < 2 || e < 576) {
      int r = e / 48;
      int cc = e - r * 48;
      int gr = (ih0 + r - 2) & (NSZ - 1);
      int gc = (iw0 + (cc >> 2) - 2) & (NSZ - 1);
      size_t off = (((size_t)gr * NSZ + gc) << 4) + ((cc & 3) << 2);
      float4 a = *reinterpret_cast<const float4*>(A + off);
      float4 b = *reinterpret_cast<const float4*>(B + off);
      float4 v;
      v.x = (a.x + sgn * b.x) * INV_SQRT2f;
      v.y = (a.y + sgn * b.y) * INV_SQRT2f;
      v.z = (a.z + sgn * b.z) * INV_SQRT2f;
      v.w = (a.w + sgn * b.w) * INV_SQRT2f;
      *reinterpret_cast<float4*>(dst + (e << 2)) = v;
    }
  }
}

// ================= Stage A: q-shift (128 -> 256) — R7 version, unchanged =================
__global__ __launch_bounds__(256) void qshift_kernel(
    const float* __restrict__ w2, const float* __restrict__ loT, float* __restrict__ mid)
{
  __shared__ __align__(16) float sIn[4][12][12][16];

  const int tid = threadIdx.x;
  const int c = tid & 15;
  const int s = tid >> 4;
  const int tw = blockIdx.x;
  const int th = blockIdx.y;
  const int b  = blockIdx.z & 3;
  const int q  = blockIdx.z >> 2;
  const int m = q >> 1, n = q & 1;
  const int j1 = m ^ n;
  const float sgn = m ? -1.0f : 1.0f;
  const int ih0 = th * 8, iw0 = tw * 8;
  const size_t plane = (size_t)128 * 128 * 16;

  stage_copy<128>(loT + ((size_t)(m * 2 + n) * 4 + b) * plane, &sIn[0][0][0][0], ih0, iw0, tid);
  stage_mix<128>(w2 + ((size_t)((0 * 2 + j1) * 3 + 0) * 4 + b) * plane,
                 w2 + ((size_t)((1 * 2 + (1 ^ j1)) * 3 + 0) * 4 + b) * plane,
                 sgn, &sIn[1][0][0][0], ih0, iw0, tid);
  stage_mix<128>(w2 + ((size_t)((0 * 2 + j1) * 3 + 1) * 4 + b) * plane,
                 w2 + ((size_t)((1 * 2 + (1 ^ j1)) * 3 + 1) * 4 + b) * plane,
                 sgn, &sIn[2][0][0][0], ih0, iw0, tid);
  stage_mix<128>(w2 + ((size_t)((0 * 2 + j1) * 3 + 2) * 4 + b) * plane,
                 w2 + ((size_t)((1 * 2 + (1 ^ j1)) * 3 + 2) * 4 + b) * plane,
                 sgn, &sIn[3][0][0][0], ih0, iw0, tid);
  __syncthreads();

  const int pw = s & 1, qw = s >> 1;
  float flp[5], fhp[5];
  #pragma unroll
  for (int j = 0; j < 5; ++j) {
    flp[j] = c_DUAL[n][0][9 - (2 * j + pw)];
    fhp[j] = c_DUAL[n][1][9 - (2 * j + pw)];
  }
  float lo2[12], h2[12];
  #pragma unroll
  for (int r = 0; r < 12; ++r) {
    float lo_v = 0.f, h_v = 0.f;
    #pragma unroll
    for (int j = 0; j < 5; ++j) {
      int x = qw + 4 - j;
      lo_v += flp[j] * sIn[0][r][x][c] + fhp[j] * sIn[1][r][x][c];
      h_v  += flp[j] * sIn[2][r][x][c] + fhp[j] * sIn[3][r][x][c];
    }
    lo2[r] = lo_v;
    h2[r] = h_v;
  }

  float* outQ = mid + ((size_t)q * 4 + b) * (size_t)(256 * 256 * 16);
  #pragma unroll
  for (int nh = 0; nh < 16; ++nh) {
    int ph = nh & 1, qh = nh >> 1;
    float v = 0.f;
    #pragma unroll
    for (int j = 0; j < 5; ++j) {
      v += c_DUAL[m][0][9 - (2 * j + ph)] * lo2[qh + 4 - j]
         + c_DUAL[m][1][9 - (2 * j + ph)] * h2[qh + 4 - j];
    }
    outQ[(((size_t)(ih0 * 2 + nh)) * 256 + (size_t)(iw0 * 2 + s)) * 16 + c] = v;
  }
}

// ================= Stage B: Farras (256 -> 512) — plane-split + col-pair remap =================
// Compute thread = (c 0..15, rh 0..1, sp 0..7): rh selects plane-pair (L: {lo,LH} / H: {HL,HH});
// sp is a column PAIR (out-cols 2sp, 2sp+1 share the same x-window). Each thread: 120 LDS reads
// per quadrant (half of R7), col pass for both parities, scatter row-pass with rh-selected taps
// (10 cndmasks, one static path). L+H partial sums combined once via __shfl_xor(.,16) after the
// q-loop. Staging, LDS layout, and barriers identical to R7 (known spill-free).
__global__ __launch_bounds__(256) void farras_kernel(
    const float* __restrict__ w1, const float* __restrict__ mid, float* __restrict__ out)
{
  __shared__ __align__(16) float sIn[4][12][12][16];

  const int tid = threadIdx.x;
  const int c  = tid & 15;
  const int rh = (tid >> 4) & 1;   // 0: L plane-pair, 1: H plane-pair
  const int sp = tid >> 5;         // col pair, out-cols 2sp / 2sp+1
  const int tw = blockIdx.x;
  const int th = blockIdx.y;
  const int b  = blockIdx.z;
  const int ih0 = th * 8, iw0 = tw * 8;
  const size_t plane = (size_t)256 * 256 * 16;

  float acc[2][16];   // [col parity][out row] — partial (L or H part only)
  #pragma unroll
  for (int i = 0; i < 16; ++i) { acc[0][i] = 0.f; acc[1][i] = 0.f; }

  const float* const sBase = &sIn[0][0][0][0] + (rh ? 2 * 2304 : 0) + c;

  #pragma unroll 1
  for (int q = 0; q < 4; ++q) {
    const int m = q >> 1, n = q & 1;
    const int j1 = m ^ n;
    const float sgn = m ? -1.0f : 1.0f;

    stage_copy<256>(mid + ((size_t)q * 4 + b) * plane, &sIn[0][0][0][0], ih0, iw0, tid);
    stage_mix<256>(w1 + ((size_t)((0 * 2 + j1) * 3 + 0) * 4 + b) * plane,
                   w1 + ((size_t)((1 * 2 + (1 ^ j1)) * 3 + 0) * 4 + b) * plane,
                   sgn, &sIn[1][0][0][0], ih0, iw0, tid);
    stage_mix<256>(w1 + ((size_t)((0 * 2 + j1) * 3 + 1) * 4 + b) * plane,
                   w1 + ((size_t)((1 * 2 + (1 ^ j1)) * 3 + 1) * 4 + b) * plane,
                   sgn, &sIn[2][0][0][0], ih0, iw0, tid);
    stage_mix<256>(w1 + ((size_t)((0 * 2 + j1) * 3 + 2) * 4 + b) * plane,
                   w1 + ((size_t)((1 * 2 + (1 ^ j1)) * 3 + 2) * 4 + b) * plane,
                   sgn, &sIn[3][0][0][0], ih0, iw0, tid);
    __syncthreads();

    // row taps for scatter: L taps (rh=0) or H taps (rh=1); 10 selects, wave-uniform sources
    float rtv[10];
    #pragma unroll
    for (int k = 0; k < 10; ++k)
      rtv[k] = rh ? c_FAR[m][1][k] : c_FAR[m][0][k];

    // col pass over this thread's plane-pair, both column parities; scatter-accumulate
    #pragma unroll
    for (int r = 0; r < 12; ++r) {
      float v0 = 0.f, v1 = 0.f;
      #pragma unroll
      for (int j = 0; j < 5; ++j) {
        const int x = sp + 4 - j;
        const float aL = sBase[(size_t)r * 192 + x * 16];          // plane 2rh
        const float aH = sBase[(size_t)r * 192 + x * 16 + 2304];   // plane 2rh+1
        v0 += c_FAR[n][0][9 - 2 * j] * aL + c_FAR[n][1][9 - 2 * j] * aH;
        v1 += c_FAR[n][0][8 - 2 * j] * aL + c_FAR[n][1][8 - 2 * j] * aH;
      }
      #pragma unroll
      for (int d = 0; d < 5; ++d) {
        const int t = r - d;
        if (t >= 0 && t <= 7) {
          acc[0][2 * t]     += rtv[2 * d + 1] * v0;
          acc[0][2 * t + 1] += rtv[2 * d]     * v0;
          acc[1][2 * t]     += rtv[2 * d + 1] * v1;
          acc[1][2 * t + 1] += rtv[2 * d]     * v1;
        }
      }
    }
    __syncthreads();   // reads done before next quadrant's staging overwrites
  }

  // combine L (rh=0) and H (rh=1) partials: partner lane = lane ^ 16 (same wave)
  #pragma unroll
  for (int nh = 0; nh < 16; ++nh) {
    acc[0][nh] += __shfl_xor(acc[0][nh], 16, 64);
    acc[1][nh] += __shfl_xor(acc[1][nh], 16, 64);
  }

  // lane rh writes column 2sp+rh (parity rh); select is static-per-element
  const int nw = 2 * sp + rh;
  #pragma unroll
  for (int nh = 0; nh < 16; ++nh) {
    const float v = rh ? acc[1][nh] : acc[0][nh];
    out[(((size_t)b * 512 + (size_t)(ih0 * 2 + nh)) * 512 + (size_t)(iw0 * 2 + nw)) * 16 + c] =
        v * 0.5f;
  }
}

extern "C" void kernel_launch(void* const* d_in, const int* in_sizes, int n_in,
                              void* d_out, int out_size, void* d_ws, size_t ws_size,
                              hipStream_t stream) {
  const float* w1 = (const float*)d_in[0];   // [2,2,3,4,256,256,16]
  const float* w2 = (const float*)d_in[1];   // [2,2,3,4,128,128,16]
  const float* lo = (const float*)d_in[2];   // [2,2,4,128,128,16]
  float* out = (float*)d_out;                // [4,512,512,16]
  float* mid = (float*)d_ws;                 // [4 quadrants][4][256][256][16] = 64 MiB

  qshift_kernel<<<dim3(16, 16, 16), 256, 0, stream>>>(w2, lo, mid);
  farras_kernel<<<dim3(32, 32, 4), 256, 0, stream>>>(w1, mid, out);
}

// Round 14
// 174.538 us; speedup vs baseline: 1.8225x; 1.8225x over previous
//
#include <hip/hip_runtime.h>

#define INV_SQRT2f 0.70710678118654752440f

// Analysis filters; synthesis filter f[k] = AF[9-k] (time reversal).
// Polyphase synthesis: out[2q+p] = sum_{j=0..4} AF[9-(2j+p)] * x[(q+2-j) mod Nin]
// Scatter form (verified R3/R11): source idx u contributes to out[2t+p] with tap AF[2(u-t)+1-p],
// t in [u-4,u] & [0,7].
__constant__ float c_FAR[2][2][10] = {
  {{0.0f, -0.08838834764832f, 0.08838834764832f, 0.69587998903400f, 0.69587998903400f,
    0.08838834764832f, -0.08838834764832f, 0.01122679215254f, 0.01122679215254f, 0.0f},
   {0.0f, -0.01122679215254f, 0.01122679215254f, 0.08838834764832f, 0.08838834764832f,
    -0.69587998903400f, 0.69587998903400f, -0.08838834764832f, -0.08838834764832f, 0.0f}},
  {{0.01122679215254f, 0.01122679215254f, -0.08838834764832f, 0.08838834764832f, 0.69587998903400f,
    0.69587998903400f, 0.08838834764832f, -0.08838834764832f, 0.0f, 0.0f},
   {0.0f, 0.0f, -0.08838834764832f, -0.08838834764832f, 0.69587998903400f,
    -0.69587998903400f, 0.08838834764832f, 0.08838834764832f, 0.01122679215254f, -0.01122679215254f}}
};
__constant__ float c_DUAL[2][2][10] = {
  {{0.03516384f, 0.0f, -0.08832942f, 0.23389032f, 0.76027237f,
    0.58751830f, 0.0f, -0.11430184f, 0.0f, 0.0f},
   {0.0f, 0.0f, -0.11430184f, 0.0f, 0.58751830f,
    -0.76027237f, 0.23389032f, 0.08832942f, 0.0f, -0.03516384f}},
  {{0.0f, 0.0f, -0.11430184f, 0.0f, 0.58751830f,
    0.76027237f, 0.23389032f, -0.08832942f, 0.0f, 0.03516384f},
   {-0.03516384f, 0.0f, 0.08832942f, 0.23389032f, -0.76027237f,
    0.58751830f, 0.0f, -0.11430184f, 0.0f, 0.0f}}
};

// ---- staging helpers (qshift only): 12x12 halo tile x 16 ch = 576 float4 ----
template<int NSZ>
__device__ __forceinline__ void stage_copy(const float* __restrict__ src, float* __restrict__ dst,
                                           int ih0, int iw0, int tid) {
  #pragma unroll
  for (int it = 0; it < 3; ++it) {
    int e = tid + (it << 8);
    if (it < 2 || e < 576) {
      int r = e / 48;
      int cc = e - r * 48;
      int gr = (ih0 + r - 2) & (NSZ - 1);
      int gc = (iw0 + (cc >> 2) - 2) & (NSZ - 1);
      float4 v = *reinterpret_cast<const float4*>(src + (((size_t)gr * NSZ + gc) << 4) + ((cc & 3) << 2));
      *reinterpret_cast<float4*>(dst + (e << 2)) = v;
    }
  }
}

template<int NSZ>
__device__ __forceinline__ void stage_mix(const float* __restrict__ A, const float* __restrict__ B,
                                          float sgn, float* __restrict__ dst,
                                          int ih0, int iw0, int tid) {
  #pragma unroll
  for (int it = 0; it < 3; ++it) {
    int e = tid + (it << 8);
    if (it < 2 || e < 576) {
      int r = e / 48;
      int cc = e - r * 48;
      int gr = (ih0 + r - 2) & (NSZ - 1);
      int gc = (iw0 + (cc >> 2) - 2) & (NSZ - 1);
      size_t off = (((size_t)gr * NSZ + gc) << 4) + ((cc & 3) << 2);
      float4 a = *reinterpret_cast<const float4*>(A + off);
      float4 b = *reinterpret_cast<const float4*>(B + off);
      float4 v;
      v.x = (a.x + sgn * b.x) * INV_SQRT2f;
      v.y = (a.y + sgn * b.y) * INV_SQRT2f;
      v.z = (a.z + sgn * b.z) * INV_SQRT2f;
      v.w = (a.w + sgn * b.w) * INV_SQRT2f;
      *reinterpret_cast<float4*>(dst + (e << 2)) = v;
    }
  }
}

// ================= Stage A: q-shift (128 -> 256) — R7 version, unchanged =================
__global__ __launch_bounds__(256) void qshift_kernel(
    const float* __restrict__ w2, const float* __restrict__ loT, float* __restrict__ mid)
{
  __shared__ __align__(16) float sIn[4][12][12][16];

  const int tid = threadIdx.x;
  const int c = tid & 15;
  const int s = tid >> 4;
  const int tw = blockIdx.x;
  const int th = blockIdx.y;
  const int b  = blockIdx.z & 3;
  const int q  = blockIdx.z >> 2;
  const int m = q >> 1, n = q & 1;
  const int j1 = m ^ n;
  const float sgn = m ? -1.0f : 1.0f;
  const int ih0 = th * 8, iw0 = tw * 8;
  const size_t plane = (size_t)128 * 128 * 16;

  stage_copy<128>(loT + ((size_t)(m * 2 + n) * 4 + b) * plane, &sIn[0][0][0][0], ih0, iw0, tid);
  stage_mix<128>(w2 + ((size_t)((0 * 2 + j1) * 3 + 0) * 4 + b) * plane,
                 w2 + ((size_t)((1 * 2 + (1 ^ j1)) * 3 + 0) * 4 + b) * plane,
                 sgn, &sIn[1][0][0][0], ih0, iw0, tid);
  stage_mix<128>(w2 + ((size_t)((0 * 2 + j1) * 3 + 1) * 4 + b) * plane,
                 w2 + ((size_t)((1 * 2 + (1 ^ j1)) * 3 + 1) * 4 + b) * plane,
                 sgn, &sIn[2][0][0][0], ih0, iw0, tid);
  stage_mix<128>(w2 + ((size_t)((0 * 2 + j1) * 3 + 2) * 4 + b) * plane,
                 w2 + ((size_t)((1 * 2 + (1 ^ j1)) * 3 + 2) * 4 + b) * plane,
                 sgn, &sIn[3][0][0][0], ih0, iw0, tid);
  __syncthreads();

  const int pw = s & 1, qw = s >> 1;
  float flp[5], fhp[5];
  #pragma unroll
  for (int j = 0; j < 5; ++j) {
    flp[j] = c_DUAL[n][0][9 - (2 * j + pw)];
    fhp[j] = c_DUAL[n][1][9 - (2 * j + pw)];
  }
  float lo2[12], h2[12];
  #pragma unroll
  for (int r = 0; r < 12; ++r) {
    float lo_v = 0.f, h_v = 0.f;
    #pragma unroll
    for (int j = 0; j < 5; ++j) {
      int x = qw + 4 - j;
      lo_v += flp[j] * sIn[0][r][x][c] + fhp[j] * sIn[1][r][x][c];
      h_v  += flp[j] * sIn[2][r][x][c] + fhp[j] * sIn[3][r][x][c];
    }
    lo2[r] = lo_v;
    h2[r] = h_v;
  }

  float* outQ = mid + ((size_t)q * 4 + b) * (size_t)(256 * 256 * 16);
  #pragma unroll
  for (int nh = 0; nh < 16; ++nh) {
    int ph = nh & 1, qh = nh >> 1;
    float v = 0.f;
    #pragma unroll
    for (int j = 0; j < 5; ++j) {
      v += c_DUAL[m][0][9 - (2 * j + ph)] * lo2[qh + 4 - j]
         + c_DUAL[m][1][9 - (2 * j + ph)] * h2[qh + 4 - j];
    }
    outQ[(((size_t)(ih0 * 2 + nh)) * 256 + (size_t)(iw0 * 2 + s)) * 16 + c] = v;
  }
}

// ================= Stage B: Farras (256 -> 512) — register col pass + colsum LDS =================
// Phase 1 (192 threads = role{L,H} x r(12) x c2(8)): global rows -> regs -> col-scatter into
// S[16] (float2) -> write colsum[role][r][nw][c] (16 b64). Phase 2 (all 256, thread=(nw=s,c)):
// 24 b32 reads + register row-gather (R7 code). LDS per block-quadrant ~5x lower than R7.
#define CS_RSTRIDE 264   // words; 264 % 32 == 8 -> phase-2 reads 2-way (free), writes <=4-way

__global__ __launch_bounds__(256) void farras_kernel(
    const float* __restrict__ w1, const float* __restrict__ mid, float* __restrict__ out)
{
  __shared__ __align__(16) float colsum[2 * 12 * CS_RSTRIDE];   // 25344 B

  const int tid = threadIdx.x;
  const int c = tid & 15;
  const int s = tid >> 4;          // phase-2 output column nw
  const int tw = blockIdx.x;
  const int th = blockIdx.y;
  const int b  = blockIdx.z;
  const int ih0 = th * 8, iw0 = tw * 8;
  const size_t plane = (size_t)256 * 256 * 16;

  // phase-1 identity: wave-aligned role split; threads 192..255 idle in phase 1
  int role, rr;
  const int c2 = tid & 7;
  if (tid < 64)       { role = 0; rr = tid >> 3; }
  else if (tid < 128) { role = 1; rr = (tid & 63) >> 3; }
  else if (tid < 160) { role = 0; rr = 8 + ((tid & 31) >> 3); }
  else                { role = 1; rr = 8 + ((tid & 31) >> 3); }
  const bool p1act = tid < 192;
  const int gr = (ih0 + rr - 2) & 255;
  const int rowoff = (gr << 12) + 2 * c2;   // words: gr*256*16 + 2*c2

  int gco[12];                              // wave-uniform per-x column offsets (words)
  #pragma unroll
  for (int x = 0; x < 12; ++x) gco[x] = ((iw0 + x - 2) & 255) << 4;

  float acc[16];
  #pragma unroll
  for (int i = 0; i < 16; ++i) acc[i] = 0.f;

  #pragma unroll 1
  for (int q = 0; q < 4; ++q) {
    const int m = q >> 1, n = q & 1;
    const int j1 = m ^ n;
    const float sgn = m ? -1.0f : 1.0f;

    if (p1act) {
      float2 S[16];
      #pragma unroll
      for (int i = 0; i < 16; ++i) S[i] = make_float2(0.f, 0.f);
      const float* tl = &c_FAR[n][0][0];   // LP column taps
      const float* tp = &c_FAR[n][1][0];   // HP column taps

      if (role == 0) {
        // plane P0 = mid (LP taps)
        {
          const float* pm = mid + ((size_t)q * 4 + b) * plane + rowoff;
          float2 v[12];
          #pragma unroll
          for (int x = 0; x < 12; ++x) v[x] = *reinterpret_cast<const float2*>(pm + gco[x]);
          #pragma unroll
          for (int x = 0; x < 12; ++x) {
            #pragma unroll
            for (int d = 0; d < 5; ++d) {
              const int qw = x - d;
              if (qw >= 0 && qw <= 7) {
                S[2 * qw].x     += tl[1 + 2 * d] * v[x].x;
                S[2 * qw].y     += tl[1 + 2 * d] * v[x].y;
                S[2 * qw + 1].x += tl[2 * d]     * v[x].x;
                S[2 * qw + 1].y += tl[2 * d]     * v[x].y;
              }
            }
          }
        }
        // plane P1 = (A0 +/- B0)*k (HP taps)
        {
          const float* pa = w1 + ((size_t)((0 * 2 + j1) * 3 + 0) * 4 + b) * plane + rowoff;
          const float* pb = w1 + ((size_t)((1 * 2 + (1 ^ j1)) * 3 + 0) * 4 + b) * plane + rowoff;
          float2 av[12], bv[12];
          #pragma unroll
          for (int x = 0; x < 12; ++x) {
            av[x] = *reinterpret_cast<const float2*>(pa + gco[x]);
            bv[x] = *reinterpret_cast<const float2*>(pb + gco[x]);
          }
          #pragma unroll
          for (int x = 0; x < 12; ++x) {
            float2 mv;
            mv.x = (av[x].x + sgn * bv[x].x) * INV_SQRT2f;
            mv.y = (av[x].y + sgn * bv[x].y) * INV_SQRT2f;
            #pragma unroll
            for (int d = 0; d < 5; ++d) {
              const int qw = x - d;
              if (qw >= 0 && qw <= 7) {
                S[2 * qw].x     += tp[1 + 2 * d] * mv.x;
                S[2 * qw].y     += tp[1 + 2 * d] * mv.y;
                S[2 * qw + 1].x += tp[2 * d]     * mv.x;
                S[2 * qw + 1].y += tp[2 * d]     * mv.y;
              }
            }
          }
        }
      } else {
        // plane P2 = (A1 +/- B1)*k (LP taps)
        {
          const float* pa = w1 + ((size_t)((0 * 2 + j1) * 3 + 1) * 4 + b) * plane + rowoff;
          const float* pb = w1 + ((size_t)((1 * 2 + (1 ^ j1)) * 3 + 1) * 4 + b) * plane + rowoff;
          float2 av[12], bv[12];
          #pragma unroll
          for (int x = 0; x < 12; ++x) {
            av[x] = *reinterpret_cast<const float2*>(pa + gco[x]);
            bv[x] = *reinterpret_cast<const float2*>(pb + gco[x]);
          }
          #pragma unroll
          for (int x = 0; x < 12; ++x) {
            float2 mv;
            mv.x = (av[x].x + sgn * bv[x].x) * INV_SQRT2f;
            mv.y = (av[x].y + sgn * bv[x].y) * INV_SQRT2f;
            #pragma unroll
            for (int d = 0; d < 5; ++d) {
              const int qw = x - d;
              if (qw >= 0 && qw <= 7) {
                S[2 * qw].x     += tl[1 + 2 * d] * mv.x;
                S[2 * qw].y     += tl[1 + 2 * d] * mv.y;
                S[2 * qw + 1].x += tl[2 * d]     * mv.x;
                S[2 * qw + 1].y += tl[2 * d]     * mv.y;
              }
            }
          }
        }
        // plane P3 = (A2 +/- B2)*k (HP taps)
        {
          const float* pa = w1 + ((size_t)((0 * 2 + j1) * 3 + 2) * 4 + b) * plane + rowoff;
          const float* pb = w1 + ((size_t)((1 * 2 + (1 ^ j1)) * 3 + 2) * 4 + b) * plane + rowoff;
          float2 av[12], bv[12];
          #pragma unroll
          for (int x = 0; x < 12; ++x) {
            av[x] = *reinterpret_cast<const float2*>(pa + gco[x]);
            bv[x] = *reinterpret_cast<const float2*>(pb + gco[x]);
          }
          #pragma unroll
          for (int x = 0; x < 12; ++x) {
            float2 mv;
            mv.x = (av[x].x + sgn * bv[x].x) * INV_SQRT2f;
            mv.y = (av[x].y + sgn * bv[x].y) * INV_SQRT2f;
            #pragma unroll
            for (int d = 0; d < 5; ++d) {
              const int qw = x - d;
              if (qw >= 0 && qw <= 7) {
                S[2 * qw].x     += tp[1 + 2 * d] * mv.x;
                S[2 * qw].y     += tp[1 + 2 * d] * mv.y;
                S[2 * qw + 1].x += tp[2 * d]     * mv.x;
                S[2 * qw + 1].y += tp[2 * d]     * mv.y;
              }
            }
          }
        }
      }
      // write S -> colsum[role][rr][nw][c2 pair]
      float* dst = &colsum[(role * 12 + rr) * CS_RSTRIDE + 2 * c2];
      #pragma unroll
      for (int nw = 0; nw < 16; ++nw)
        *reinterpret_cast<float2*>(dst + nw * 16) = S[nw];
    }
    __syncthreads();

    // phase 2: row pass in registers (R7's proven gather)
    {
      float lo2[12], h2[12];
      #pragma unroll
      for (int r = 0; r < 12; ++r) {
        lo2[r] = colsum[(0 * 12 + r) * CS_RSTRIDE + s * 16 + c];
        h2[r]  = colsum[(1 * 12 + r) * CS_RSTRIDE + s * 16 + c];
      }
      #pragma unroll
      for (int nh = 0; nh < 16; ++nh) {
        const int ph = nh & 1, qh = nh >> 1;
        float v = 0.f;
        #pragma unroll
        for (int j = 0; j < 5; ++j) {
          v += c_FAR[m][0][9 - (2 * j + ph)] * lo2[qh + 4 - j]
             + c_FAR[m][1][9 - (2 * j + ph)] * h2[qh + 4 - j];
        }
        acc[nh] += v;
      }
    }
    __syncthreads();   // before next quadrant overwrites colsum
  }

  #pragma unroll
  for (int nh = 0; nh < 16; ++nh) {
    size_t gh = (size_t)(ih0 * 2 + nh);
    size_t gw = (size_t)(iw0 * 2 + s);
    out[(((size_t)b * 512 + gh) * 512 + gw) * 16 + c] = acc[nh] * 0.5f;
  }
}

extern "C" void kernel_launch(void* const* d_in, const int* in_sizes, int n_in,
                              void* d_out, int out_size, void* d_ws, size_t ws_size,
                              hipStream_t stream) {
  const float* w1 = (const float*)d_in[0];   // [2,2,3,4,256,256,16]
  const float* w2 = (const float*)d_in[1];   // [2,2,3,4,128,128,16]
  const float* lo = (const float*)d_in[2];   // [2,2,4,128,128,16]
  float* out = (float*)d_out;                // [4,512,512,16]
  float* mid = (float*)d_ws;                 // [4 quadrants][4][256][256][16] = 64 MiB

  qshift_kernel<<<dim3(16, 16, 16), 256, 0, stream>>>(w2, lo, mid);
  farras_kernel<<<dim3(32, 32, 4), 256, 0, stream>>>(w1, mid, out);
}